// Round 3
// baseline (141.244 us; speedup 1.0000x reference)
//
#include <hip/hip_runtime.h>
#include <math.h>

// Residual 4-level E8-root VQ.
// Outputs (concat, all float32 in d_out):
//   [0, 8N)          quantized_ste = (qsum + x) - x   (matches jnp rounding)
//   [8N, 12N)        idx_stack[4][N] as float (values 0..239)
//   [12N]            qerr = mean((x - qsum)^2)
//
// Numerics are engineered to match the reference bit-for-bit where possible:
//  - r2[j] == 2.0 exactly for every E8 root; d2 = fl(fl(res2+2) - 2*dot),
//    realized as fmaf(-2, dot, s) (2*dot is exact -> identical rounding).
//  - clip(.,0) dropped: true distances >= 0, and at most ONE root can have
//    rounded d2 <= 0 (roots are >= sqrt(2) apart), so argmin with strict-<
//    scan in reference index order is identical to argmin(clip(d2)).
//  - Type-1 dots (+-r_i +- r_j): exact under ANY summation order (other 6
//    products are exact zeros), so 1 add each.
//  - Type-2 dots: emulate SEQUENTIAL k=0..7 accumulation (BLAS microkernel
//    order) via shared prefix tables (D depth-4, E depth-5, F depth-6) +
//    IEEE negation symmetry fl(-a-b) == -fl(a+b); chain sign tracked at
//    compile time. Sharing computes the IDENTICAL float op sequence once
//    -> bit-exact (F[2e]=E[e]+h5 / F[2e+1]=E[e]-h5 are exactly the ops the
//    per-candidate code performed).
//  - res2: numpy pairwise tree ((q0+q1)+(q2+q3))+((q4+q5)+(q6+q7)).
//  - fp contract OFF so the compiler can't re-fuse r*r into the sum tree.
//
// R3 changes (post-mortem R2: launch_bounds(256,4) clamped VGPR to 64 and
// spilled ~48B/row to scratch -> WRITE_SIZE doubled, dur regressed):
//  - plain __launch_bounds__(256): allocator free, no spill.
//  - 6 chains (2 for T1, 4 for T2), LOCAL index <= 55 everywhere -> inline
//    constant in v_cndmask (no v_mov literal materialization).
//  - F[32] depth-6 prefix: -96 adds/level, bit-exact sharing.
//  - T2 scan as 4 separate 32-trip fully-unrolled loops (compile-time t ->
//    all parity/sign logic folds; small trip count unrolls reliably).

__global__ __launch_bounds__(256) void e8_quant_kernel(
    const float* __restrict__ x, const float* __restrict__ roots,
    float* __restrict__ out, float* __restrict__ partials, int nrow) {
#pragma clang fp contract(off)
  __shared__ float lroots[240 * 8];
  __shared__ float wred[4];
  for (int t = threadIdx.x; t < 240 * 8; t += 256) lroots[t] = roots[t];
  __syncthreads();

  const int row = blockIdx.x * 256 + threadIdx.x;
  const bool active = row < nrow;
  float e = 0.f;

  if (active) {
    const float4 xa = *(const float4*)(x + (size_t)row * 8);
    const float4 xb = *(const float4*)(x + (size_t)row * 8 + 4);
    float xr[8] = {xa.x, xa.y, xa.z, xa.w, xb.x, xb.y, xb.z, xb.w};
    float qs[8] = {0.f, 0.f, 0.f, 0.f, 0.f, 0.f, 0.f, 0.f};
    float r[8];
#pragma unroll
    for (int k = 0; k < 8; ++k) r[k] = xr[k];

    float* out_idx = out + (size_t)nrow * 8;

#pragma unroll 1
    for (int lvl = 0; lvl < 4; ++lvl) {
      // res2, numpy pairwise order
      const float q0 = r[0] * r[0], q1 = r[1] * r[1], q2 = r[2] * r[2],
                  q3 = r[3] * r[3], q4 = r[4] * r[4], q5 = r[5] * r[5],
                  q6 = r[6] * r[6], q7 = r[7] * r[7];
      const float res2 = ((q0 + q1) + (q2 + q3)) + ((q4 + q5) + (q6 + q7));
      const float s = res2 + 2.0f;

      // 6 independent argmin chains over index-contiguous candidate blocks:
      //   ch0: T1 [0,56)   ch1: T1 [56,112)
      //   ch2: T2 t[0,32)  ch3: t[32,64)  ch4: t[64,96)  ch5: t[96,128)
      // Each chain tracks a LOCAL index (<= 55) -> inline constant in
      // v_cndmask. Strict '<' keeps the earliest index on rounded-d2 ties.
      const float INF = 3.4028235e38f;
      float bst[6] = {INF, INF, INF, INF, INF, INF};
      int bxl[6] = {0, 0, 0, 0, 0, 0};

      auto upd = [&](int ch, float d2v, int lidx) {
        const bool c = d2v < bst[ch];      // uses OLD best
        bst[ch] = fminf(bst[ch], d2v);     // 1-deep min chain, ILP w/ cmp
        bxl[ch] = c ? lidx : bxl[ch];      // lidx <= 55: inline constant
      };

      // ---- Type-1: 112 roots, pairs (i<j), sign order (++,+-,-+,--) ----
      // Pair p (0..27): chain p/14, local candidate base (p%14)*4 <= 52.
      {
        int p = 0;
#pragma unroll
        for (int i = 0; i < 8; ++i) {
#pragma unroll
          for (int j = i + 1; j < 8; ++j) {
            const int ch = (p < 14) ? 0 : 1;
            const int l0 = (p - ch * 14) * 4;
            const float a = r[i] + r[j];  // dot for (+,+); -(a) for (-,-)
            const float b = r[i] - r[j];  // dot for (+,-); -(b) for (-,+)
            upd(ch, fmaf(-2.f, a, s), l0 + 0);
            upd(ch, fmaf(-2.f, b, s), l0 + 1);
            upd(ch, fmaf(2.f, b, s), l0 + 2);
            upd(ch, fmaf(2.f, a, s), l0 + 3);
            ++p;
          }
        }
      }

      // ---- Type-2: 128 roots, even-parity sign masks m, increasing m ----
      const float h0 = 0.5f * r[0], h1 = 0.5f * r[1], h2 = 0.5f * r[2],
                  h3 = 0.5f * r[3], h4 = 0.5f * r[4], h5 = 0.5f * r[5],
                  h6 = 0.5f * r[6], h7 = 0.5f * r[7];
      // sequential-prefix tables, stored up-to-sign (sigma = -1 iff bit0 set)
      const float A = h0 + h1, B = h0 - h1;
      const float C0 = A + h2, C1 = A - h2, C2 = B + h2, C3 = B - h2;
      const float D[8] = {C0 + h3, C0 - h3, C1 + h3, C1 - h3,
                          C2 + h3, C2 - h3, C3 + h3, C3 - h3};
      float E[16];
#pragma unroll
      for (int q = 0; q < 8; ++q) {
        E[2 * q] = D[q] + h4;      // depth-5 prefix, '+' h4 (V-space)
        E[2 * q + 1] = D[q] - h4;
      }
      float F[32];
#pragma unroll
      for (int q = 0; q < 16; ++q) {
        F[2 * q] = E[q] + h5;      // depth-6 prefix, '+' h5 (V-space)
        F[2 * q + 1] = E[q] - h5;
      }

      // Per candidate t: m = (t<<1)|parity(t); chain value V relates to the
      // true sequential prefix by sigma = (b0 ? -1 : +1); effective add-sign
      // in V-space for h_k is '+' iff (bit_k(m) == b0). All compile-time.
#define T2BLOCK(BASE, CH)                                                   \
  _Pragma("unroll") for (int it = 0; it < 32; ++it) {                       \
    const int t = (BASE) + it;                                              \
    const int m = (t << 1) | (__popc(t) & 1);                               \
    const int b0 = m & 1;                                                   \
    const bool Xa = (((m >> 1) & 1) == b0);                                 \
    const int cidx =                                                        \
        Xa ? ((((m >> 2) & 1) == b0) ? 0 : 1)                               \
           : ((((m >> 2) & 1) == b0) ? 2 : 3);                              \
    const int di = cidx * 2 + ((((m >> 3) & 1) == b0) ? 0 : 1);             \
    const int ei = di * 2 + ((((m >> 4) & 1) == b0) ? 0 : 1);               \
    const int fi = ei * 2 + ((((m >> 5) & 1) == b0) ? 0 : 1);               \
    float v = F[fi];                                                        \
    v = ((((m >> 6) & 1) == b0) ? (v + h6) : (v - h6));                     \
    v = ((((m >> 7) & 1) == b0) ? (v + h7) : (v - h7));                     \
    const float d2v = b0 ? fmaf(2.f, v, s) : fmaf(-2.f, v, s);              \
    upd((CH), d2v, it);                                                     \
  }

      T2BLOCK(0, 2)
      T2BLOCK(32, 3)
      T2BLOCK(64, 4)
      T2BLOCK(96, 5)
#undef T2BLOCK

      // ---- ordered tournament merge: strict '<' keeps the lower-index
      // block on rounded ties -> first-index argmin globally. ----
      const bool cT1 = bst[1] < bst[0];
      const float mT1 = fminf(bst[0], bst[1]);
      const int iT1 = cT1 ? (bxl[1] + 56) : bxl[0];

      const bool cU = bst[3] < bst[2];
      const float mU = fminf(bst[2], bst[3]);
      const int iU = cU ? (bxl[3] + 144) : (bxl[2] + 112);

      const bool cV = bst[5] < bst[4];
      const float mV = fminf(bst[4], bst[5]);
      const int iV = cV ? (bxl[5] + 208) : (bxl[4] + 176);

      const bool cW = mV < mU;
      const float mW = fminf(mU, mV);
      const int iW = cW ? iV : iU;

      const int bi = (mW < mT1) ? iW : iT1;

      out_idx[(size_t)lvl * nrow + row] = (float)bi;

      // gather winning root from LDS; update qsum and residual (ref order)
      const float4 ra = *(const float4*)(lroots + bi * 8);
      const float4 rb = *(const float4*)(lroots + bi * 8 + 4);
      qs[0] += ra.x; qs[1] += ra.y; qs[2] += ra.z; qs[3] += ra.w;
      qs[4] += rb.x; qs[5] += rb.y; qs[6] += rb.z; qs[7] += rb.w;
#pragma unroll
      for (int k = 0; k < 8; ++k) r[k] = xr[k] - qs[k];
    }

    // quantized_ste = (qsum + x) - x, left-assoc like the reference
    float o[8];
#pragma unroll
    for (int k = 0; k < 8; ++k) o[k] = (qs[k] + xr[k]) - xr[k];
    *(float4*)(out + (size_t)row * 8) = make_float4(o[0], o[1], o[2], o[3]);
    *(float4*)(out + (size_t)row * 8 + 4) = make_float4(o[4], o[5], o[6], o[7]);

    // qerr partial: sum (x - qsum)^2  (== r after last level)
#pragma unroll
    for (int k = 0; k < 8; ++k) e = fmaf(r[k], r[k], e);
  }

  // block reduction of e -> partials[blockIdx.x]
#pragma unroll
  for (int off = 32; off > 0; off >>= 1) e += __shfl_down(e, off, 64);
  const int lane = threadIdx.x & 63, wv = threadIdx.x >> 6;
  if (lane == 0) wred[wv] = e;
  __syncthreads();
  if (threadIdx.x == 0)
    partials[blockIdx.x] = (wred[0] + wred[1]) + (wred[2] + wred[3]);
}

__global__ __launch_bounds__(256) void qerr_reduce_kernel(
    const float* __restrict__ partials, float* __restrict__ out, int n,
    size_t pos, float scale) {
#pragma clang fp contract(off)
  __shared__ float wred[4];
  float e = 0.f;
  for (int i = threadIdx.x; i < n; i += 256) e += partials[i];
#pragma unroll
  for (int off = 32; off > 0; off >>= 1) e += __shfl_down(e, off, 64);
  const int lane = threadIdx.x & 63, wv = threadIdx.x >> 6;
  if (lane == 0) wred[wv] = e;
  __syncthreads();
  if (threadIdx.x == 0)
    out[pos] = ((wred[0] + wred[1]) + (wred[2] + wred[3])) * scale;
}

extern "C" void kernel_launch(void* const* d_in, const int* in_sizes, int n_in,
                              void* d_out, int out_size, void* d_ws,
                              size_t ws_size, hipStream_t stream) {
  const float* x = (const float*)d_in[0];
  const float* roots = (const float*)d_in[1];
  float* out = (float*)d_out;
  float* partials = (float*)d_ws;

  const int nrow = in_sizes[0] / 8;
  const int nblocks = (nrow + 255) / 256;

  e8_quant_kernel<<<nblocks, 256, 0, stream>>>(x, roots, out, partials, nrow);

  const size_t qerr_pos = (size_t)nrow * 12;
  const float scale = 1.0f / (float)((size_t)nrow * 8);  // 1/2^22, exact
  qerr_reduce_kernel<<<1, 256, 0, stream>>>(partials, out, nblocks, qerr_pos,
                                            scale);
}

// Round 4
// 110.310 us; speedup vs baseline: 1.2804x; 1.2804x over previous
//
#include <hip/hip_runtime.h>
#include <math.h>

// Residual 4-level E8-root VQ — analytic argmin with exact fallback.
//
// Outputs (concat, all float32 in d_out):
//   [0, 8N)          quantized_ste = (qsum + x) - x   (matches jnp rounding)
//   [8N, 12N)        idx_stack[4][N] as float (values 0..239)
//   [12N]            qerr = mean((x - qsum)^2)
//
// ---- Why analytic argmin is reference-exact ----
// Reference: d2[j] = fl(fl(res2 + 2) - fl(2*dot_j)), dot_j accumulated
// SEQUENTIALLY k=0..7; argmin with first-index tie-break on ROUNDED values.
// E8 structure gives the true-max-dot root in closed form:
//   Type-1 (roots +-e_i +- e_j): best dot = A1 + A2, the two largest |r_k|,
//     with root signs = signs of those coordinates. Runner-up dot = A1 + A3
//     (gap A2-A3); sign-flip variants trail by >= 2*A2 >= 2*(A2-A3).
//   Type-2 (roots (+-1/2)^8, even # of minus): best mask = signbits(r);
//     if parity odd, flip the bit of the smallest |r_k| (costs Amin).
//     Valid runner-up trails by (Amin+Amin2) [even] or (Amin2-Amin) [odd].
// Error bound: each reference fl-d2 deviates from the analytic value by
// <= 7u*Sabs + u*M <= 8u*M  (u = 2^-24, Sabs = sum|r_k|, M = res2+2+2*Sabs;
// T1 dots round once, T2 dots accumulate 7 adds bounded by Sabs/2).
// Comparing two candidates: slop <= 16u*M = 2^-20*M.  If every decision
// margin exceeds thr = 2^-17*M (8x the bound, absorbing fast-path rounding),
// rounding can neither reorder candidates nor create a rounded tie, so the
// analytic index == the reference scan's index.  Any failing margin
// (includes all tie cases: zero coords, equal magnitudes, cross-type ties)
// sends the whole wave to the bit-exact serial scan (cold path, verbatim
// reference semantics).  Expected fallback ~1e-5 per row-level.
//
// ---- Exact-path numerics (unchanged from verified R1 kernel) ----
//  - r2[j] == 2.0 exactly; d2 = fmaf(-/+2, dot, s) == fl(s - fl(2*dot)).
//  - clip(.,0) dropped: at most one root can have rounded d2 <= 0.
//  - T1 dots: single rounding fl(r_i +- r_j).
//  - T2 dots: direct sequential signed accumulation of h_k = 0.5*r_k
//    (products exact), i.e. literally the reference order.
//  - res2: numpy pairwise tree; fp contract OFF everywhere.

__global__ __launch_bounds__(256) void e8_quant_kernel(
    const float* __restrict__ x, const float* __restrict__ roots,
    float* __restrict__ out, float* __restrict__ partials, int nrow) {
#pragma clang fp contract(off)
  __shared__ float lroots[240 * 8];
  __shared__ float wred[4];
  for (int t = threadIdx.x; t < 240 * 8; t += 256) lroots[t] = roots[t];
  __syncthreads();

  const int row = blockIdx.x * 256 + threadIdx.x;
  const bool active = row < nrow;
  float e = 0.f;

  if (active) {
    const float4 xa = *(const float4*)(x + (size_t)row * 8);
    const float4 xb = *(const float4*)(x + (size_t)row * 8 + 4);
    float xr[8] = {xa.x, xa.y, xa.z, xa.w, xb.x, xb.y, xb.z, xb.w};
    float qs[8] = {0.f, 0.f, 0.f, 0.f, 0.f, 0.f, 0.f, 0.f};
    float r[8];
#pragma unroll
    for (int k = 0; k < 8; ++k) r[k] = xr[k];

    float* out_idx = out + (size_t)nrow * 8;

#pragma unroll 1
    for (int lvl = 0; lvl < 4; ++lvl) {
      // res2 in numpy pairwise order (feeds exact path + thr scale)
      const float q0 = r[0] * r[0], q1 = r[1] * r[1], q2 = r[2] * r[2],
                  q3 = r[3] * r[3], q4 = r[4] * r[4], q5 = r[5] * r[5],
                  q6 = r[6] * r[6], q7 = r[7] * r[7];
      const float res2 = ((q0 + q1) + (q2 + q3)) + ((q4 + q5) + (q6 + q7));
      const float s = res2 + 2.0f;

      // ---- per-coordinate magnitude / sign metadata ----
      const unsigned u0 = __float_as_uint(r[0]), u1 = __float_as_uint(r[1]),
                     u2 = __float_as_uint(r[2]), u3 = __float_as_uint(r[3]),
                     u4 = __float_as_uint(r[4]), u5 = __float_as_uint(r[5]),
                     u6 = __float_as_uint(r[6]), u7 = __float_as_uint(r[7]);
      const float m0v = __uint_as_float(u0 & 0x7fffffffu),
                  m1v = __uint_as_float(u1 & 0x7fffffffu),
                  m2v = __uint_as_float(u2 & 0x7fffffffu),
                  m3v = __uint_as_float(u3 & 0x7fffffffu),
                  m4v = __uint_as_float(u4 & 0x7fffffffu),
                  m5v = __uint_as_float(u5 & 0x7fffffffu),
                  m6v = __uint_as_float(u6 & 0x7fffffffu),
                  m7v = __uint_as_float(u7 & 0x7fffffffu);
      const int sb0 = (int)(u0 >> 31), sb1 = (int)(u1 >> 31),
                sb2 = (int)(u2 >> 31), sb3 = (int)(u3 >> 31),
                sb4 = (int)(u4 >> 31), sb5 = (int)(u5 >> 31),
                sb6 = (int)(u6 >> 31), sb7 = (int)(u7 >> 31);
      const int msk = sb0 | (sb1 << 1) | (sb2 << 2) | (sb3 << 3) |
                      (sb4 << 4) | (sb5 << 5) | (sb6 << 6) | (sb7 << 7);
      const int par = __popc(msk) & 1;
      const float Sabs =
          ((m0v + m1v) + (m2v + m3v)) + ((m4v + m5v) + (m6v + m7v));

      // keys: position | signbit<<3
      const int K0 = 0 | (sb0 << 3), K1 = 1 | (sb1 << 3), K2 = 2 | (sb2 << 3),
                K3 = 3 | (sb3 << 3), K4 = 4 | (sb4 << 3), K5 = 5 | (sb5 << 3),
                K6 = 6 | (sb6 << 3), K7 = 7 | (sb7 << 3);

      // ---- top-3 magnitudes (A1>=A2>=A3), keys for A1,A2 ----
      // pair stage
      const bool g01 = m1v > m0v;
      const float h01 = fmaxf(m0v, m1v), l01 = fminf(m0v, m1v);
      const int hk01 = g01 ? K1 : K0, lk01 = g01 ? K0 : K1;
      const bool g23 = m3v > m2v;
      const float h23 = fmaxf(m2v, m3v), l23 = fminf(m2v, m3v);
      const int hk23 = g23 ? K3 : K2, lk23 = g23 ? K2 : K3;
      const bool g45 = m5v > m4v;
      const float h45 = fmaxf(m4v, m5v), l45 = fminf(m4v, m5v);
      const int hk45 = g45 ? K5 : K4, lk45 = g45 ? K4 : K5;
      const bool g67 = m7v > m6v;
      const float h67 = fmaxf(m6v, m7v), l67 = fminf(m6v, m7v);
      const int hk67 = g67 ? K7 : K6, lk67 = g67 ? K6 : K7;
      // quad 0 (pairs 01,23)
      const bool qg0 = h23 > h01;
      const float qh0 = fmaxf(h01, h23);
      const int qhk0 = qg0 ? hk23 : hk01;
      const float sA0 = qg0 ? l23 : l01;  // lo of winner pair
      const int sAk0 = qg0 ? lk23 : lk01;
      const float sB0 = qg0 ? h01 : h23;  // hi of loser pair
      const int sBk0 = qg0 ? hk01 : hk23;
      const float loL0 = qg0 ? l01 : l23;  // lo of loser pair
      const bool qx0 = sB0 > sA0;
      const float qs0v = fmaxf(sA0, sB0);
      const int qsk0 = qx0 ? sBk0 : sAk0;
      const float qt0 = qx0 ? fmaxf(sA0, loL0) : sB0;  // 3rd of quad
      // quad 1 (pairs 45,67)
      const bool qg1 = h67 > h45;
      const float qh1 = fmaxf(h45, h67);
      const int qhk1 = qg1 ? hk67 : hk45;
      const float sA1 = qg1 ? l67 : l45;
      const int sAk1 = qg1 ? lk67 : lk45;
      const float sB1 = qg1 ? h45 : h67;
      const int sBk1 = qg1 ? hk45 : hk67;
      const float loL1 = qg1 ? l45 : l67;
      const bool qx1 = sB1 > sA1;
      const float qs1v = fmaxf(sA1, sB1);
      const int qsk1 = qx1 ? sBk1 : sAk1;
      const float qt1 = qx1 ? fmaxf(sA1, loL1) : sB1;
      // final
      const bool fg = qh1 > qh0;
      const float A1v = fmaxf(qh0, qh1);
      const int A1K = fg ? qhk1 : qhk0;
      const float fA = fg ? qs1v : qs0v;  // 2nd of winner quad
      const int fAk = fg ? qsk1 : qsk0;
      const float fB = fg ? qh0 : qh1;  // hi of loser quad
      const int fBk = fg ? qhk0 : qhk1;
      const float tW = fg ? qt1 : qt0;   // 3rd of winner quad
      const float sL = fg ? qs0v : qs1v;  // 2nd of loser quad
      const bool fh = fB > fA;
      const float A2v = fmaxf(fA, fB);
      const int A2K = fh ? fBk : fAk;
      const float A3v = fh ? fmaxf(fA, sL) : fmaxf(tW, fB);

      // ---- bottom-2 magnitudes (Amin, Amin2), key for Amin ----
      const bool n0 = l23 < l01;
      const float mn0 = fminf(l01, l23);
      const int mnk0 = n0 ? lk23 : lk01;
      const float pr0 = n0 ? h23 : h01;  // partner (hi of min's pair)
      const float ot0 = fmaxf(l01, l23); // other lo in this duo
      const bool n1 = l67 < l45;
      const float mn1 = fminf(l45, l67);
      const int mnk1 = n1 ? lk67 : lk45;
      const float pr1 = n1 ? h67 : h45;
      const float ot1 = fmaxf(l45, l67);
      const bool nf = mn1 < mn0;
      const float Aminv = fminf(mn0, mn1);
      const int AminK = nf ? mnk1 : mnk0;
      const float prW = nf ? pr1 : pr0;
      const float otW = nf ? ot1 : ot0;
      const float mnL = fmaxf(mn0, mn1);
      const float Amin2v = fminf(prW, fminf(otW, mnL));

      // ---- analytic best dots + indices ----
      const float dT1 = A1v + A2v;
      const float halfS = 0.5f * Sabs;
      const float dT2 = par ? (halfS - Aminv) : halfS;

      // T1 index: pair (i<j) enumeration + sign offset (++,+-,-+,--)
      const int p1 = A1K & 7, p2 = A2K & 7;
      const int s1b = A1K >> 3, s2b = A2K >> 3;
      const bool o12 = p1 < p2;
      const int imn = o12 ? p1 : p2, jmx = o12 ? p2 : p1;
      const int sIb = o12 ? s1b : s2b, sJb = o12 ? s2b : s1b;
      const int pbase = imn * 7 - ((imn * (imn - 1)) >> 1) + (jmx - imn - 1);
      const int t1idx = (pbase << 2) | (sIb << 1) | sJb;

      // T2 index: mask -> t = m>>1 (m = (t<<1)|parity(t) is a bijection)
      const int mp = AminK & 7;
      const int mf = par ? (msk ^ (1 << mp)) : msk;
      const int t2idx = 112 + (mf >> 1);

      // ---- margins ----
      const bool useT1 = dT1 > dT2;
      const float thr =
          (res2 + 2.0f * Sabs + 2.0f) * 7.6293945e-06f;  // 2^-17 * M
      const bool okc = fabsf(dT1 - dT2) > thr;
      const bool okt = useT1 ? ((A2v - A3v) > thr)
                             : (par ? ((Amin2v - Aminv) > thr)
                                    : ((Aminv + Amin2v) > thr));
      const int ok = okc && okt;

      int bi = useT1 ? t1idx : t2idx;

      if (__any(!ok)) {
        // ---- exact serial scan (cold; verbatim reference semantics) ----
        float best = 3.4028235e38f;
        int be = 0;
        int ci = 0;
#pragma unroll
        for (int i = 0; i < 8; ++i) {
#pragma unroll
          for (int j = i + 1; j < 8; ++j) {
            const float a = r[i] + r[j];  // dot (+,+); -(a) for (-,-)
            const float b = r[i] - r[j];  // dot (+,-); -(b) for (-,+)
            float d;
            d = fmaf(-2.f, a, s);
            if (d < best) { best = d; be = ci + 0; }
            d = fmaf(-2.f, b, s);
            if (d < best) { best = d; be = ci + 1; }
            d = fmaf(2.f, b, s);
            if (d < best) { best = d; be = ci + 2; }
            d = fmaf(2.f, a, s);
            if (d < best) { best = d; be = ci + 3; }
            ci += 4;
          }
        }
        const float h0 = 0.5f * r[0], h1 = 0.5f * r[1], h2 = 0.5f * r[2],
                    h3 = 0.5f * r[3], h4 = 0.5f * r[4], h5 = 0.5f * r[5],
                    h6 = 0.5f * r[6], h7 = 0.5f * r[7];
        for (int t = 0; t < 128; ++t) {
          const int m = (t << 1) | (__popc(t) & 1);
          // direct sequential signed accumulation == reference fl order
          float v = (m & 1) ? -h0 : h0;
          v = (m & 2) ? (v - h1) : (v + h1);
          v = (m & 4) ? (v - h2) : (v + h2);
          v = (m & 8) ? (v - h3) : (v + h3);
          v = (m & 16) ? (v - h4) : (v + h4);
          v = (m & 32) ? (v - h5) : (v + h5);
          v = (m & 64) ? (v - h6) : (v + h6);
          v = (m & 128) ? (v - h7) : (v + h7);
          const float d = fmaf(-2.f, v, s);
          if (d < best) { best = d; be = 112 + t; }
        }
        bi = be;
      }

      out_idx[(size_t)lvl * nrow + row] = (float)bi;

      // gather winning root from LDS; update qsum and residual (ref order)
      const float4 ra = *(const float4*)(lroots + bi * 8);
      const float4 rb = *(const float4*)(lroots + bi * 8 + 4);
      qs[0] += ra.x; qs[1] += ra.y; qs[2] += ra.z; qs[3] += ra.w;
      qs[4] += rb.x; qs[5] += rb.y; qs[6] += rb.z; qs[7] += rb.w;
#pragma unroll
      for (int k = 0; k < 8; ++k) r[k] = xr[k] - qs[k];
    }

    // quantized_ste = (qsum + x) - x, left-assoc like the reference
    float o[8];
#pragma unroll
    for (int k = 0; k < 8; ++k) o[k] = (qs[k] + xr[k]) - xr[k];
    *(float4*)(out + (size_t)row * 8) = make_float4(o[0], o[1], o[2], o[3]);
    *(float4*)(out + (size_t)row * 8 + 4) = make_float4(o[4], o[5], o[6], o[7]);

    // qerr partial: sum (x - qsum)^2  (== r after last level)
#pragma unroll
    for (int k = 0; k < 8; ++k) e = fmaf(r[k], r[k], e);
  }

  // block reduction of e -> partials[blockIdx.x]
#pragma unroll
  for (int off = 32; off > 0; off >>= 1) e += __shfl_down(e, off, 64);
  const int lane = threadIdx.x & 63, wv = threadIdx.x >> 6;
  if (lane == 0) wred[wv] = e;
  __syncthreads();
  if (threadIdx.x == 0)
    partials[blockIdx.x] = (wred[0] + wred[1]) + (wred[2] + wred[3]);
}

__global__ __launch_bounds__(256) void qerr_reduce_kernel(
    const float* __restrict__ partials, float* __restrict__ out, int n,
    size_t pos, float scale) {
#pragma clang fp contract(off)
  __shared__ float wred[4];
  float e = 0.f;
  for (int i = threadIdx.x; i < n; i += 256) e += partials[i];
#pragma unroll
  for (int off = 32; off > 0; off >>= 1) e += __shfl_down(e, off, 64);
  const int lane = threadIdx.x & 63, wv = threadIdx.x >> 6;
  if (lane == 0) wred[wv] = e;
  __syncthreads();
  if (threadIdx.x == 0)
    out[pos] = ((wred[0] + wred[1]) + (wred[2] + wred[3])) * scale;
}

extern "C" void kernel_launch(void* const* d_in, const int* in_sizes, int n_in,
                              void* d_out, int out_size, void* d_ws,
                              size_t ws_size, hipStream_t stream) {
  const float* x = (const float*)d_in[0];
  const float* roots = (const float*)d_in[1];
  float* out = (float*)d_out;
  float* partials = (float*)d_ws;

  const int nrow = in_sizes[0] / 8;
  const int nblocks = (nrow + 255) / 256;

  e8_quant_kernel<<<nblocks, 256, 0, stream>>>(x, roots, out, partials, nrow);

  const size_t qerr_pos = (size_t)nrow * 12;
  const float scale = 1.0f / (float)((size_t)nrow * 8);  // 1/2^22, exact
  qerr_reduce_kernel<<<1, 256, 0, stream>>>(partials, out, nblocks, qerr_pos,
                                            scale);
}

// Round 5
// 92.887 us; speedup vs baseline: 1.5206x; 1.1876x over previous
//
#include <hip/hip_runtime.h>
#include <math.h>

// Residual 4-level E8-root VQ — analytic argmin with decomposed exact fallback.
//
// Outputs (concat, all float32 in d_out):
//   [0, 8N)          quantized_ste = (qsum + x) - x   (matches jnp rounding)
//   [8N, 12N)        idx_stack[4][N] as float (values 0..239)
//   [12N]            qerr = mean((x - qsum)^2)
//
// ---- Analytic argmin (see R4) ----
// Reference: d2[j] = fl(fl(res2+2) - fl(2*dot_j)), dot_j sequential k=0..7;
// argmin, first-index tie-break on ROUNDED values.
//   T1 best: two largest |r_k| (A1,A2), signs of those coords.
//   T2 best: sign mask of r; odd parity flips the smallest-|r_k| bit.
// Error budget (u = 2^-24, M = res2 + 2 + 2*Sabs):
//   each ref d2 deviates from its analytic value by <= 2.75u*M
//   (T1 dot rounds once; T2: 7 adds each bounded by Sabs/2 <= M/4, + u*M).
//   two-candidate compare slop <= 5.5u*M; our fp margins err <= ~4u*M.
// thr = 2^-19*M = 32u*M  =>  passing margin guarantees true gap >= 28u*M
// > 5.5u*M: rounding can neither reorder nor create a rounded tie.
//
// ---- R5 decomposed slow paths (replaces whole-wave 240-scan) ----
//   a1 = T1 index certain (A2-A3 > thr; also covers sign flips, gap >= 2*A2)
//   a2 = T2 index certain (odd: Amin2-Amin; even: Amin+Amin2)
//   c  = cross-type margin (|dT1-dT2| > thr)
//   !a1 -> exact T1-only scan (112 cands, ref order, strict <)
//   !a2 -> exact T2-only scan (128 cands, sequential fl order, strict <)
//   !c (indices certain) -> exact ref d2 of the two candidates in ~30 ops:
//        d1 = fmaf(-2, fl(A1+A2), s)   [T1 ref dot == fl(A1+A2): six exact-
//                                       zero adds; fp add commutes]
//        d2x = fmaf(-2, seqsum, s)     [seqsum = sequential sum of |h_k|,
//                                       term at Amin position negated if odd
//                                       parity — bitwise == ref accumulation]
//   pick: c ? (dT1 > dT2 ? T1 : T2) : (d1 <= d2x ? i1 : i2)
//   ('<=' == global first-index: all T1 indices < all T2 indices).
//
// ---- Exact-path numerics (verified absmax=0 in R1/R4) ----
//  - r2[j] == 2.0 exactly; d2 = fmaf(+-2, dot, s) == fl(s - fl(2*dot)).
//  - clip(.,0) dropped: at most one root can have rounded d2 <= 0.
//  - res2: numpy pairwise tree; fp contract OFF everywhere.

__global__ __launch_bounds__(256) void e8_quant_kernel(
    const float* __restrict__ x, const float* __restrict__ roots,
    float* __restrict__ out, float* __restrict__ partials, int nrow) {
#pragma clang fp contract(off)
  __shared__ float lroots[240 * 8];
  __shared__ float wred[4];
  for (int t = threadIdx.x; t < 240 * 8; t += 256) lroots[t] = roots[t];
  __syncthreads();

  const int row = blockIdx.x * 256 + threadIdx.x;
  const bool active = row < nrow;
  float e = 0.f;

  if (active) {
    const float4 xa = *(const float4*)(x + (size_t)row * 8);
    const float4 xb = *(const float4*)(x + (size_t)row * 8 + 4);
    float xr[8] = {xa.x, xa.y, xa.z, xa.w, xb.x, xb.y, xb.z, xb.w};
    float qs[8] = {0.f, 0.f, 0.f, 0.f, 0.f, 0.f, 0.f, 0.f};
    float r[8];
#pragma unroll
    for (int k = 0; k < 8; ++k) r[k] = xr[k];

    float* out_idx = out + (size_t)nrow * 8;

#pragma unroll 1
    for (int lvl = 0; lvl < 4; ++lvl) {
      // res2 in numpy pairwise order (feeds exact path + thr scale)
      const float q0 = r[0] * r[0], q1 = r[1] * r[1], q2 = r[2] * r[2],
                  q3 = r[3] * r[3], q4 = r[4] * r[4], q5 = r[5] * r[5],
                  q6 = r[6] * r[6], q7 = r[7] * r[7];
      const float res2 = ((q0 + q1) + (q2 + q3)) + ((q4 + q5) + (q6 + q7));
      const float s = res2 + 2.0f;

      // ---- per-coordinate magnitude / sign metadata ----
      const unsigned u0 = __float_as_uint(r[0]), u1 = __float_as_uint(r[1]),
                     u2 = __float_as_uint(r[2]), u3 = __float_as_uint(r[3]),
                     u4 = __float_as_uint(r[4]), u5 = __float_as_uint(r[5]),
                     u6 = __float_as_uint(r[6]), u7 = __float_as_uint(r[7]);
      const float m0v = __uint_as_float(u0 & 0x7fffffffu),
                  m1v = __uint_as_float(u1 & 0x7fffffffu),
                  m2v = __uint_as_float(u2 & 0x7fffffffu),
                  m3v = __uint_as_float(u3 & 0x7fffffffu),
                  m4v = __uint_as_float(u4 & 0x7fffffffu),
                  m5v = __uint_as_float(u5 & 0x7fffffffu),
                  m6v = __uint_as_float(u6 & 0x7fffffffu),
                  m7v = __uint_as_float(u7 & 0x7fffffffu);
      const int sb0 = (int)(u0 >> 31), sb1 = (int)(u1 >> 31),
                sb2 = (int)(u2 >> 31), sb3 = (int)(u3 >> 31),
                sb4 = (int)(u4 >> 31), sb5 = (int)(u5 >> 31),
                sb6 = (int)(u6 >> 31), sb7 = (int)(u7 >> 31);
      const int msk = sb0 | (sb1 << 1) | (sb2 << 2) | (sb3 << 3) |
                      (sb4 << 4) | (sb5 << 5) | (sb6 << 6) | (sb7 << 7);
      const int par = __popc(msk) & 1;
      const float Sabs =
          ((m0v + m1v) + (m2v + m3v)) + ((m4v + m5v) + (m6v + m7v));

      // keys: position | signbit<<3
      const int K0 = 0 | (sb0 << 3), K1 = 1 | (sb1 << 3), K2 = 2 | (sb2 << 3),
                K3 = 3 | (sb3 << 3), K4 = 4 | (sb4 << 3), K5 = 5 | (sb5 << 3),
                K6 = 6 | (sb6 << 3), K7 = 7 | (sb7 << 3);

      // ---- top-3 magnitudes (A1>=A2>=A3), keys for A1,A2 ----
      const bool g01 = m1v > m0v;
      const float h01 = fmaxf(m0v, m1v), l01 = fminf(m0v, m1v);
      const int hk01 = g01 ? K1 : K0, lk01 = g01 ? K0 : K1;
      const bool g23 = m3v > m2v;
      const float h23 = fmaxf(m2v, m3v), l23 = fminf(m2v, m3v);
      const int hk23 = g23 ? K3 : K2, lk23 = g23 ? K2 : K3;
      const bool g45 = m5v > m4v;
      const float h45 = fmaxf(m4v, m5v), l45 = fminf(m4v, m5v);
      const int hk45 = g45 ? K5 : K4, lk45 = g45 ? K4 : K5;
      const bool g67 = m7v > m6v;
      const float h67 = fmaxf(m6v, m7v), l67 = fminf(m6v, m7v);
      const int hk67 = g67 ? K7 : K6, lk67 = g67 ? K6 : K7;
      // quad 0 (pairs 01,23)
      const bool qg0 = h23 > h01;
      const float qh0 = fmaxf(h01, h23);
      const int qhk0 = qg0 ? hk23 : hk01;
      const float sA0 = qg0 ? l23 : l01;
      const int sAk0 = qg0 ? lk23 : lk01;
      const float sB0 = qg0 ? h01 : h23;
      const int sBk0 = qg0 ? hk01 : hk23;
      const float loL0 = qg0 ? l01 : l23;
      const bool qx0 = sB0 > sA0;
      const float qs0v = fmaxf(sA0, sB0);
      const int qsk0 = qx0 ? sBk0 : sAk0;
      const float qt0 = qx0 ? fmaxf(sA0, loL0) : sB0;
      // quad 1 (pairs 45,67)
      const bool qg1 = h67 > h45;
      const float qh1 = fmaxf(h45, h67);
      const int qhk1 = qg1 ? hk67 : hk45;
      const float sA1 = qg1 ? l67 : l45;
      const int sAk1 = qg1 ? lk67 : lk45;
      const float sB1 = qg1 ? h45 : h67;
      const int sBk1 = qg1 ? hk45 : hk67;
      const float loL1 = qg1 ? l45 : l67;
      const bool qx1 = sB1 > sA1;
      const float qs1v = fmaxf(sA1, sB1);
      const int qsk1 = qx1 ? sBk1 : sAk1;
      const float qt1 = qx1 ? fmaxf(sA1, loL1) : sB1;
      // final
      const bool fg = qh1 > qh0;
      const float A1v = fmaxf(qh0, qh1);
      const int A1K = fg ? qhk1 : qhk0;
      const float fA = fg ? qs1v : qs0v;
      const int fAk = fg ? qsk1 : qsk0;
      const float fB = fg ? qh0 : qh1;
      const int fBk = fg ? qhk0 : qhk1;
      const float tW = fg ? qt1 : qt0;
      const float sL = fg ? qs0v : qs1v;
      const bool fh = fB > fA;
      const float A2v = fmaxf(fA, fB);
      const int A2K = fh ? fBk : fAk;
      const float A3v = fh ? fmaxf(fA, sL) : fmaxf(tW, fB);

      // ---- bottom-2 magnitudes (Amin, Amin2), key for Amin ----
      const bool n0 = l23 < l01;
      const float mn0 = fminf(l01, l23);
      const int mnk0 = n0 ? lk23 : lk01;
      const float pr0 = n0 ? h23 : h01;
      const float ot0 = fmaxf(l01, l23);
      const bool n1 = l67 < l45;
      const float mn1 = fminf(l45, l67);
      const int mnk1 = n1 ? lk67 : lk45;
      const float pr1 = n1 ? h67 : h45;
      const float ot1 = fmaxf(l45, l67);
      const bool nf = mn1 < mn0;
      const float Aminv = fminf(mn0, mn1);
      const int AminK = nf ? mnk1 : mnk0;
      const float prW = nf ? pr1 : pr0;
      const float otW = nf ? ot1 : ot0;
      const float mnL = fmaxf(mn0, mn1);
      const float Amin2v = fminf(prW, fminf(otW, mnL));

      // ---- analytic best dots + indices ----
      const float dT1r = A1v + A2v;  // == exact ref dot of T1 best (1 round)
      const float halfS = 0.5f * Sabs;
      const float dT2 = par ? (halfS - Aminv) : halfS;

      // T1 index: pair (i<j) enumeration + sign offset (++,+-,-+,--)
      const int p1 = A1K & 7, p2 = A2K & 7;
      const int s1b = A1K >> 3, s2b = A2K >> 3;
      const bool o12 = p1 < p2;
      const int imn = o12 ? p1 : p2, jmx = o12 ? p2 : p1;
      const int sIb = o12 ? s1b : s2b, sJb = o12 ? s2b : s1b;
      const int pbase = imn * 7 - ((imn * (imn - 1)) >> 1) + (jmx - imn - 1);
      const int t1idx = (pbase << 2) | (sIb << 1) | sJb;

      // T2 index: mask -> t = m>>1 (m = (t<<1)|parity(t) is a bijection)
      const int mp = AminK & 7;
      const int mf = par ? (msk ^ (1 << mp)) : msk;
      const int t2idx = 112 + (mf >> 1);

      // ---- margins (thr = 2^-19 * M = 32u*M) ----
      const float thr =
          (res2 + 2.0f * Sabs + 2.0f) * 1.9073486e-06f;
      const bool a1 = (A2v - A3v) > thr;
      const bool a2 = par ? ((Amin2v - Aminv) > thr)
                          : ((Aminv + Amin2v) > thr);
      const bool c = fabsf(dT1r - dT2) > thr;

      float d1 = fmaf(-2.f, dT1r, s);  // exact ref d2 of t1idx (when a1)
      int i1 = t1idx;
      float d2x = 0.f;
      int i2 = t2idx;

      // ---- slow path A: T1 index ambiguous -> exact T1-only scan ----
      if (__any(!a1)) {
        if (!a1) {
          float best = 3.4028235e38f;
          int be = 0;
          int ci = 0;
#pragma unroll
          for (int i = 0; i < 8; ++i) {
#pragma unroll
            for (int j = i + 1; j < 8; ++j) {
              const float a = r[i] + r[j];  // dot (+,+); -(a) for (-,-)
              const float b = r[i] - r[j];  // dot (+,-); -(b) for (-,+)
              float d;
              d = fmaf(-2.f, a, s);
              if (d < best) { best = d; be = ci + 0; }
              d = fmaf(-2.f, b, s);
              if (d < best) { best = d; be = ci + 1; }
              d = fmaf(2.f, b, s);
              if (d < best) { best = d; be = ci + 2; }
              d = fmaf(2.f, a, s);
              if (d < best) { best = d; be = ci + 3; }
              ci += 4;
            }
          }
          d1 = best;
          i1 = be;
        }
      }

      // ---- slow path B: T2 index ambiguous -> exact T2-only scan ----
      if (__any(!a2)) {
        if (!a2) {
          const float h0 = 0.5f * r[0], h1 = 0.5f * r[1], h2 = 0.5f * r[2],
                      h3 = 0.5f * r[3], h4 = 0.5f * r[4], h5 = 0.5f * r[5],
                      h6 = 0.5f * r[6], h7 = 0.5f * r[7];
          float best2 = 3.4028235e38f;
          int bt = 0;
#pragma unroll
          for (int t = 0; t < 128; ++t) {
            const int m = (t << 1) | (__popc(t) & 1);
            // direct sequential signed accumulation == reference fl order
            float v = (m & 1) ? -h0 : h0;
            v = (m & 2) ? (v - h1) : (v + h1);
            v = (m & 4) ? (v - h2) : (v + h2);
            v = (m & 8) ? (v - h3) : (v + h3);
            v = (m & 16) ? (v - h4) : (v + h4);
            v = (m & 32) ? (v - h5) : (v + h5);
            v = (m & 64) ? (v - h6) : (v + h6);
            v = (m & 128) ? (v - h7) : (v + h7);
            const float d = fmaf(-2.f, v, s);
            if (d < best2) { best2 = d; bt = t; }
          }
          d2x = best2;
          i2 = 112 + bt;
        }
      }

      // ---- slow path C: cross ambiguous, T2 index certain -> exact ref
      // d2 of analytic T2 candidate via sequential sum of |h_k| with the
      // Amin-position term negated iff parity odd. Bitwise == reference. ----
      if (__any(!c && a2)) {
        if (!c && a2) {
          const int flip = par ? mp : 8;  // 8 = never
          float t0 = 0.5f * m0v, t1v = 0.5f * m1v, t2v = 0.5f * m2v,
                t3v = 0.5f * m3v, t4v = 0.5f * m4v, t5v = 0.5f * m5v,
                t6v = 0.5f * m6v, t7v = 0.5f * m7v;
          t0 = (flip == 0) ? -t0 : t0;
          t1v = (flip == 1) ? -t1v : t1v;
          t2v = (flip == 2) ? -t2v : t2v;
          t3v = (flip == 3) ? -t3v : t3v;
          t4v = (flip == 4) ? -t4v : t4v;
          t5v = (flip == 5) ? -t5v : t5v;
          t6v = (flip == 6) ? -t6v : t6v;
          t7v = (flip == 7) ? -t7v : t7v;
          float v = t0;
          v = v + t1v;
          v = v + t2v;
          v = v + t3v;
          v = v + t4v;
          v = v + t5v;
          v = v + t6v;
          v = v + t7v;
          d2x = fmaf(-2.f, v, s);
        }
      }

      // ---- final pick ----
      // c: type certain by margin -> analytic compare.
      // !c: exact compare; '<=' keeps T1 (lower global indices) on ties.
      const int bi = c ? ((dT1r > dT2) ? i1 : i2)
                       : ((d1 <= d2x) ? i1 : i2);

      out_idx[(size_t)lvl * nrow + row] = (float)bi;

      // gather winning root from LDS; update qsum and residual (ref order)
      const float4 ra = *(const float4*)(lroots + bi * 8);
      const float4 rb = *(const float4*)(lroots + bi * 8 + 4);
      qs[0] += ra.x; qs[1] += ra.y; qs[2] += ra.z; qs[3] += ra.w;
      qs[4] += rb.x; qs[5] += rb.y; qs[6] += rb.z; qs[7] += rb.w;
#pragma unroll
      for (int k = 0; k < 8; ++k) r[k] = xr[k] - qs[k];
    }

    // quantized_ste = (qsum + x) - x, left-assoc like the reference
    float o[8];
#pragma unroll
    for (int k = 0; k < 8; ++k) o[k] = (qs[k] + xr[k]) - xr[k];
    *(float4*)(out + (size_t)row * 8) = make_float4(o[0], o[1], o[2], o[3]);
    *(float4*)(out + (size_t)row * 8 + 4) = make_float4(o[4], o[5], o[6], o[7]);

    // qerr partial: sum (x - qsum)^2  (== r after last level)
#pragma unroll
    for (int k = 0; k < 8; ++k) e = fmaf(r[k], r[k], e);
  }

  // block reduction of e -> partials[blockIdx.x]
#pragma unroll
  for (int off = 32; off > 0; off >>= 1) e += __shfl_down(e, off, 64);
  const int lane = threadIdx.x & 63, wv = threadIdx.x >> 6;
  if (lane == 0) wred[wv] = e;
  __syncthreads();
  if (threadIdx.x == 0)
    partials[blockIdx.x] = (wred[0] + wred[1]) + (wred[2] + wred[3]);
}

__global__ __launch_bounds__(256) void qerr_reduce_kernel(
    const float* __restrict__ partials, float* __restrict__ out, int n,
    size_t pos, float scale) {
#pragma clang fp contract(off)
  __shared__ float wred[4];
  float e = 0.f;
  for (int i = threadIdx.x; i < n; i += 256) e += partials[i];
#pragma unroll
  for (int off = 32; off > 0; off >>= 1) e += __shfl_down(e, off, 64);
  const int lane = threadIdx.x & 63, wv = threadIdx.x >> 6;
  if (lane == 0) wred[wv] = e;
  __syncthreads();
  if (threadIdx.x == 0)
    out[pos] = ((wred[0] + wred[1]) + (wred[2] + wred[3])) * scale;
}

extern "C" void kernel_launch(void* const* d_in, const int* in_sizes, int n_in,
                              void* d_out, int out_size, void* d_ws,
                              size_t ws_size, hipStream_t stream) {
  const float* x = (const float*)d_in[0];
  const float* roots = (const float*)d_in[1];
  float* out = (float*)d_out;
  float* partials = (float*)d_ws;

  const int nrow = in_sizes[0] / 8;
  const int nblocks = (nrow + 255) / 256;

  e8_quant_kernel<<<nblocks, 256, 0, stream>>>(x, roots, out, partials, nrow);

  const size_t qerr_pos = (size_t)nrow * 12;
  const float scale = 1.0f / (float)((size_t)nrow * 8);  // 1/2^22, exact
  qerr_reduce_kernel<<<1, 256, 0, stream>>>(partials, out, nblocks, qerr_pos,
                                            scale);
}

// Round 7
// 90.276 us; speedup vs baseline: 1.5646x; 1.0289x over previous
//
#include <hip/hip_runtime.h>
#include <math.h>

// Residual 4-level E8-root VQ — analytic argmin + cheap exact fallbacks,
// 2 rows per thread.
//
// Outputs (concat, all float32 in d_out):
//   [0, 8N)          quantized_ste = (qsum + x) - x   (matches jnp rounding)
//   [8N, 12N)        idx_stack[4][N] as float (values 0..239)
//   [12N]            qerr = mean((x - qsum)^2)
//
// ---- Analytic argmin (R4/R5, verified absmax=0) ----
// Reference: d2[j] = fl(fl(res2+2) - fl(2*dot_j)), dot_j sequential k=0..7;
// argmin, first-index tie-break on ROUNDED values.
//   T1 best: two largest |r_k| (A1,A2), signs of those coords.
//   T2 best: sign mask of r; odd parity flips the smallest-|r_k| bit.
// Error budget (u = 2^-24, M = res2 + 2 + 2*Sabs):
//   each ref d2 deviates from its analytic value by <= 2.75u*M; pairwise
//   compare slop <= 5.5u*M; our fp margin measurement error <= 3.5u*M.
// thr = 2^-20*M = 16u*M: a passing margin guarantees true gap >= 12.5u*M
// > 5.5u*M -> rounding can neither reorder nor create a rounded tie.
//
// ---- R6 fallback decomposition (cost of ambiguity) ----
//   !a1 (A2-A3 <= thr):
//     if Amin > thr: wrong-sign T1 candidates trail by 2*Amin > 2thr ->
//       28-pair best-sign EXACT scan (dot = fl(|ri|+|rj|), == ref bits),
//       ascending enum order, strict '<' => first-index argmin over T1.
//     else: full 112-candidate exact scan (rare: a coord ~ 0).
//   !a2, odd parity (Amin2-Amin <= thr):
//     if 2*Amin2 > thr: any triple-flip trails best single-flip by
//       Amin2+Amin3 >= 2*Amin2 > thr -> argmin is a SINGLE-BIT flip.
//       Evaluate all 8 exact seq-sum d2s, tie-break on smaller t (= mask>>1).
//     else: full 128 scan (both smallest coords ~ 0; ~1e-12 rare).
//   !a2, even parity (Amin+Amin2 <= thr): full 128 scan (both coords ~ 0).
//   !c with a2: exact ref d2 of the analytic T2 candidate in ~10 ops.
//   pick: c ? (dT1 > dT2 ? i1 : i2) : (d1 <= d2x ? i1 : i2)
//   ('<=' == global first-index: all T1 indices < all T2 indices).
//
// ---- 2 rows/thread (R6) ----
// block covers 512 rows: slot0 = rows [b*512, b*512+256) (thread t -> row
// b*512+t), slot1 = +256. Two independent dep chains per lane double ILP.
// qerr partials stay BIT-IDENTICAL to the verified 1-row scheme: slot0's
// shfl+wred reduction over its 256 rows equals old block 2b exactly (same
// lane->row map, same tree), written to partials[2b]; slot1 -> partials[2b+1].
//
// ---- Exact-path numerics (verified absmax=0 in R1/R4/R5) ----
//  - r2[j] == 2.0 exactly; d2 = fmaf(+-2, dot, s) == fl(s - fl(2*dot)).
//  - clip(.,0) dropped: at most one root can have rounded d2 <= 0.
//  - res2: numpy pairwise tree; fp contract OFF everywhere.

__global__ __launch_bounds__(256) void e8_quant_kernel(
    const float* __restrict__ x, const float* __restrict__ roots,
    float* __restrict__ out, float* __restrict__ partials, int nrow) {
#pragma clang fp contract(off)
  __shared__ float lroots[240 * 8];
  __shared__ float wred0[4];
  __shared__ float wred1[4];
  for (int t = threadIdx.x; t < 240 * 8; t += 256) lroots[t] = roots[t];
  __syncthreads();

  const int row0 = blockIdx.x * 512 + threadIdx.x;
  const int row1 = row0 + 256;
  const bool act0 = row0 < nrow;
  const bool act1 = row1 < nrow;
  float* out_idx = out + (size_t)nrow * 8;

  float xr0[8], qs0[8], r0[8];
  float xr1[8], qs1[8], r1[8];
  float e0 = 0.f, e1 = 0.f;

  if (act0) {
    const float4 xa = *(const float4*)(x + (size_t)row0 * 8);
    const float4 xb = *(const float4*)(x + (size_t)row0 * 8 + 4);
    xr0[0] = xa.x; xr0[1] = xa.y; xr0[2] = xa.z; xr0[3] = xa.w;
    xr0[4] = xb.x; xr0[5] = xb.y; xr0[6] = xb.z; xr0[7] = xb.w;
#pragma unroll
    for (int k = 0; k < 8; ++k) { qs0[k] = 0.f; r0[k] = xr0[k]; }
  }
  if (act1) {
    const float4 xa = *(const float4*)(x + (size_t)row1 * 8);
    const float4 xb = *(const float4*)(x + (size_t)row1 * 8 + 4);
    xr1[0] = xa.x; xr1[1] = xa.y; xr1[2] = xa.z; xr1[3] = xa.w;
    xr1[4] = xb.x; xr1[5] = xb.y; xr1[6] = xb.z; xr1[7] = xb.w;
#pragma unroll
    for (int k = 0; k < 8; ++k) { qs1[k] = 0.f; r1[k] = xr1[k]; }
  }

  auto level_step = [&](int lvl, float (&xr)[8], float (&qs)[8],
                        float (&r)[8], int row) {
    // res2 in numpy pairwise order (feeds exact path + thr scale)
    float q[8];
#pragma unroll
    for (int k = 0; k < 8; ++k) q[k] = r[k] * r[k];
    const float res2 = ((q[0] + q[1]) + (q[2] + q[3])) +
                       ((q[4] + q[5]) + (q[6] + q[7]));
    const float s = res2 + 2.0f;

    // per-coordinate magnitude / sign metadata
    float mg[8];
    int sb[8];
#pragma unroll
    for (int k = 0; k < 8; ++k) {
      const unsigned u = __float_as_uint(r[k]);
      mg[k] = __uint_as_float(u & 0x7fffffffu);
      sb[k] = (int)(u >> 31);
    }
    const int msk = sb[0] | (sb[1] << 1) | (sb[2] << 2) | (sb[3] << 3) |
                    (sb[4] << 4) | (sb[5] << 5) | (sb[6] << 6) | (sb[7] << 7);
    const int par = __popc(msk) & 1;
    const float Sabs = ((mg[0] + mg[1]) + (mg[2] + mg[3])) +
                       ((mg[4] + mg[5]) + (mg[6] + mg[7]));

    // keys: position | signbit<<3
    const int K0 = 0 | (sb[0] << 3), K1 = 1 | (sb[1] << 3),
              K2 = 2 | (sb[2] << 3), K3 = 3 | (sb[3] << 3),
              K4 = 4 | (sb[4] << 3), K5 = 5 | (sb[5] << 3),
              K6 = 6 | (sb[6] << 3), K7 = 7 | (sb[7] << 3);

    // ---- top-3 magnitudes (A1>=A2>=A3), keys for A1,A2 ----
    const bool g01 = mg[1] > mg[0];
    const float h01 = fmaxf(mg[0], mg[1]), l01 = fminf(mg[0], mg[1]);
    const int hk01 = g01 ? K1 : K0, lk01 = g01 ? K0 : K1;
    const bool g23 = mg[3] > mg[2];
    const float h23 = fmaxf(mg[2], mg[3]), l23 = fminf(mg[2], mg[3]);
    const int hk23 = g23 ? K3 : K2, lk23 = g23 ? K2 : K3;
    const bool g45 = mg[5] > mg[4];
    const float h45 = fmaxf(mg[4], mg[5]), l45 = fminf(mg[4], mg[5]);
    const int hk45 = g45 ? K5 : K4, lk45 = g45 ? K4 : K5;
    const bool g67 = mg[7] > mg[6];
    const float h67 = fmaxf(mg[6], mg[7]), l67 = fminf(mg[6], mg[7]);
    const int hk67 = g67 ? K7 : K6, lk67 = g67 ? K6 : K7;
    // quad 0 (pairs 01,23)
    const bool qg0 = h23 > h01;
    const float qh0 = fmaxf(h01, h23);
    const int qhk0 = qg0 ? hk23 : hk01;
    const float sA0 = qg0 ? l23 : l01;
    const int sAk0 = qg0 ? lk23 : lk01;
    const float sB0 = qg0 ? h01 : h23;
    const int sBk0 = qg0 ? hk01 : hk23;
    const float loL0 = qg0 ? l01 : l23;
    const bool qx0 = sB0 > sA0;
    const float qs0v = fmaxf(sA0, sB0);
    const int qsk0 = qx0 ? sBk0 : sAk0;
    const float qt0 = qx0 ? fmaxf(sA0, loL0) : sB0;
    // quad 1 (pairs 45,67)
    const bool qg1 = h67 > h45;
    const float qh1 = fmaxf(h45, h67);
    const int qhk1 = qg1 ? hk67 : hk45;
    const float sA1 = qg1 ? l67 : l45;
    const int sAk1 = qg1 ? lk67 : lk45;
    const float sB1 = qg1 ? h45 : h67;
    const int sBk1 = qg1 ? hk45 : hk67;
    const float loL1 = qg1 ? l45 : l67;
    const bool qx1 = sB1 > sA1;
    const float qs1v = fmaxf(sA1, sB1);
    const int qsk1 = qx1 ? sBk1 : sAk1;
    const float qt1 = qx1 ? fmaxf(sA1, loL1) : sB1;
    // final
    const bool fg = qh1 > qh0;
    const float A1v = fmaxf(qh0, qh1);
    const int A1K = fg ? qhk1 : qhk0;
    const float fA = fg ? qs1v : qs0v;
    const int fAk = fg ? qsk1 : qsk0;
    const float fB = fg ? qh0 : qh1;
    const int fBk = fg ? qhk0 : qhk1;
    const float tW = fg ? qt1 : qt0;
    const float sL = fg ? qs0v : qs1v;
    const bool fh = fB > fA;
    const float A2v = fmaxf(fA, fB);
    const int A2K = fh ? fBk : fAk;
    const float A3v = fh ? fmaxf(fA, sL) : fmaxf(tW, fB);

    // ---- bottom-2 magnitudes (Amin, Amin2), key for Amin ----
    const bool n0 = l23 < l01;
    const float mn0 = fminf(l01, l23);
    const int mnk0 = n0 ? lk23 : lk01;
    const float pr0 = n0 ? h23 : h01;
    const float ot0 = fmaxf(l01, l23);
    const bool n1 = l67 < l45;
    const float mn1 = fminf(l45, l67);
    const int mnk1 = n1 ? lk67 : lk45;
    const float pr1 = n1 ? h67 : h45;
    const float ot1 = fmaxf(l45, l67);
    const bool nf = mn1 < mn0;
    const float Aminv = fminf(mn0, mn1);
    const int AminK = nf ? mnk1 : mnk0;
    const float prW = nf ? pr1 : pr0;
    const float otW = nf ? ot1 : ot0;
    const float mnL = fmaxf(mn0, mn1);
    const float Amin2v = fminf(prW, fminf(otW, mnL));

    // ---- analytic best dots + indices ----
    const float dT1r = A1v + A2v;  // == exact ref dot of T1 best (1 round)
    const float halfS = 0.5f * Sabs;
    const float dT2 = par ? (halfS - Aminv) : halfS;

    // T1 index: pair (i<j) enumeration + sign offset (++,+-,-+,--)
    const int p1 = A1K & 7, p2 = A2K & 7;
    const int s1b = A1K >> 3, s2b = A2K >> 3;
    const bool o12 = p1 < p2;
    const int imn = o12 ? p1 : p2, jmx = o12 ? p2 : p1;
    const int sIb = o12 ? s1b : s2b, sJb = o12 ? s2b : s1b;
    const int pbase = imn * 7 - ((imn * (imn - 1)) >> 1) + (jmx - imn - 1);
    const int t1idx = (pbase << 2) | (sIb << 1) | sJb;

    // T2 index: mask -> t = m>>1 (m = (t<<1)|parity(t) is a bijection)
    const int mp = AminK & 7;
    const int mf = par ? (msk ^ (1 << mp)) : msk;
    const int t2idx = 112 + (mf >> 1);

    // ---- margins (thr = 2^-20 * M = 16u*M) ----
    const float thr = (res2 + 2.0f * Sabs + 2.0f) * 0x1.0p-20f;
    const bool a1 = (A2v - A3v) > thr;
    const bool a2 = par ? ((Amin2v - Aminv) > thr)
                        : ((Aminv + Amin2v) > thr);
    const bool c = fabsf(dT1r - dT2) > thr;

    float d1 = fmaf(-2.f, dT1r, s);  // exact ref d2 of t1idx (when a1)
    int i1 = t1idx;
    float d2x = 0.f;
    int i2 = t2idx;

    // ---- slow path A: T1 index ambiguous ----
    if (__any(!a1)) {
      if (!a1) {
        if (Aminv > thr) {
          // 28-pair best-sign exact scan; wrong-sign combos trail by
          // 2*Amin > 2thr -> cannot win or tie. Ascending enum order,
          // strict '<' => first-index argmin over all 112.
          float best = 3.4028235e38f;
          int bidx = 0;
          int ci = 0;
#pragma unroll
          for (int i = 0; i < 8; ++i) {
#pragma unroll
            for (int j = i + 1; j < 8; ++j) {
              const float aa = mg[i] + mg[j];  // == ref fl(ri+rj) up to sign
              const float d = fmaf(-2.f, aa, s);
              const int idx = (ci << 2) | (sb[i] << 1) | sb[j];
              if (d < best) { best = d; bidx = idx; }
              ++ci;
            }
          }
          d1 = best;
          i1 = bidx;
        } else {
          // full exact T1 scan (a coordinate ~ 0; rare)
          float best = 3.4028235e38f;
          int be = 0;
          int ci = 0;
#pragma unroll
          for (int i = 0; i < 8; ++i) {
#pragma unroll
            for (int j = i + 1; j < 8; ++j) {
              const float a = r[i] + r[j];
              const float b = r[i] - r[j];
              float d;
              d = fmaf(-2.f, a, s);
              if (d < best) { best = d; be = ci + 0; }
              d = fmaf(-2.f, b, s);
              if (d < best) { best = d; be = ci + 1; }
              d = fmaf(2.f, b, s);
              if (d < best) { best = d; be = ci + 2; }
              d = fmaf(2.f, a, s);
              if (d < best) { best = d; be = ci + 3; }
              ci += 4;
            }
          }
          d1 = best;
          i1 = be;
        }
      }
    }

    // ---- slow path B: T2 index ambiguous ----
    if (__any(!a2)) {
      if (!a2) {
        float h[8];
#pragma unroll
        for (int k = 0; k < 8; ++k) h[k] = 0.5f * r[k];  // exact
        const bool cheap = par && ((Amin2v + Amin2v) > thr);
        if (cheap) {
          // odd parity: rounded argmin must be a single-bit flip
          // (triple flips trail by Amin2+Amin3 >= 2*Amin2 > thr).
          // Evaluate all 8 exact sequential-sum d2s; tie-break on
          // smaller t (reference scans t ascending).
          float best2 = 3.4028235e38f;
          int bt = 0;
#pragma unroll
          for (int k = 0; k < 8; ++k) {
            const int mk = msk ^ (1 << k);
            float v = (mk & 1) ? -h[0] : h[0];
#pragma unroll
            for (int j = 1; j < 8; ++j)
              v = (mk & (1 << j)) ? (v - h[j]) : (v + h[j]);
            const float d = fmaf(-2.f, v, s);
            const int t = mk >> 1;
            const bool take = (d < best2) || (d == best2 && t < bt);
            best2 = take ? d : best2;
            bt = take ? t : bt;
          }
          d2x = best2;
          i2 = 112 + bt;
        } else {
          // full exact T2 scan (two coords ~ 0; very rare). Small code:
          // runtime mask, sequential fl order == reference.
          float best2 = 3.4028235e38f;
          int bt = 0;
#pragma unroll 1
          for (int t = 0; t < 128; ++t) {
            const int m = (t << 1) | (__popc(t) & 1);
            float v = (m & 1) ? -h[0] : h[0];
#pragma unroll
            for (int j = 1; j < 8; ++j)
              v = (m & (1 << j)) ? (v - h[j]) : (v + h[j]);
            const float d = fmaf(-2.f, v, s);
            if (d < best2) { best2 = d; bt = t; }
          }
          d2x = best2;
          i2 = 112 + bt;
        }
      }
    }

    // ---- slow path C: cross ambiguous, T2 index certain -> exact ref
    // d2 of analytic T2 candidate (sequential |h| sum, Amin term negated
    // iff odd parity; bitwise == reference accumulation). ----
    if (__any(!c && a2)) {
      if (!c && a2) {
        const int flip = par ? mp : 8;  // 8 = never
        float v = (flip == 0) ? -(0.5f * mg[0]) : (0.5f * mg[0]);
#pragma unroll
        for (int j = 1; j < 8; ++j) {
          const float tj = 0.5f * mg[j];
          v = (flip == j) ? (v - tj) : (v + tj);
        }
        d2x = fmaf(-2.f, v, s);
      }
    }

    // ---- final pick ----
    // c: type certain by margin -> analytic compare (dot values are exact
    //    regardless of within-type index ambiguity).
    // !c: exact compare; '<=' keeps T1 (lower global indices) on ties.
    const int bi = c ? ((dT1r > dT2) ? i1 : i2)
                     : ((d1 <= d2x) ? i1 : i2);

    out_idx[(size_t)lvl * nrow + row] = (float)bi;

    // gather winning root from LDS; update qsum and residual (ref order)
    const float4 ra = *(const float4*)(lroots + bi * 8);
    const float4 rb = *(const float4*)(lroots + bi * 8 + 4);
    qs[0] += ra.x; qs[1] += ra.y; qs[2] += ra.z; qs[3] += ra.w;
    qs[4] += rb.x; qs[5] += rb.y; qs[6] += rb.z; qs[7] += rb.w;
#pragma unroll
    for (int k = 0; k < 8; ++k) r[k] = xr[k] - qs[k];
  };

#pragma unroll 1
  for (int lvl = 0; lvl < 4; ++lvl) {
    if (act0) level_step(lvl, xr0, qs0, r0, row0);
    if (act1) level_step(lvl, xr1, qs1, r1, row1);
  }

  if (act0) {
    float o[8];
#pragma unroll
    for (int k = 0; k < 8; ++k) o[k] = (qs0[k] + xr0[k]) - xr0[k];
    *(float4*)(out + (size_t)row0 * 8) = make_float4(o[0], o[1], o[2], o[3]);
    *(float4*)(out + (size_t)row0 * 8 + 4) =
        make_float4(o[4], o[5], o[6], o[7]);
#pragma unroll
    for (int k = 0; k < 8; ++k) e0 = fmaf(r0[k], r0[k], e0);
  }
  if (act1) {
    float o[8];
#pragma unroll
    for (int k = 0; k < 8; ++k) o[k] = (qs1[k] + xr1[k]) - xr1[k];
    *(float4*)(out + (size_t)row1 * 8) = make_float4(o[0], o[1], o[2], o[3]);
    *(float4*)(out + (size_t)row1 * 8 + 4) =
        make_float4(o[4], o[5], o[6], o[7]);
#pragma unroll
    for (int k = 0; k < 8; ++k) e1 = fmaf(r1[k], r1[k], e1);
  }

  // block reduction: two partials, bit-identical to the old 1-row/thread
  // scheme (slot0 == old block 2b, slot1 == old block 2b+1).
#pragma unroll
  for (int off = 32; off > 0; off >>= 1) e0 += __shfl_down(e0, off, 64);
#pragma unroll
  for (int off = 32; off > 0; off >>= 1) e1 += __shfl_down(e1, off, 64);
  const int lane = threadIdx.x & 63, wv = threadIdx.x >> 6;
  if (lane == 0) { wred0[wv] = e0; wred1[wv] = e1; }
  __syncthreads();
  if (threadIdx.x == 0) {
    partials[2 * blockIdx.x] =
        (wred0[0] + wred0[1]) + (wred0[2] + wred0[3]);
    partials[2 * blockIdx.x + 1] =
        (wred1[0] + wred1[1]) + (wred1[2] + wred1[3]);
  }
}

__global__ __launch_bounds__(256) void qerr_reduce_kernel(
    const float* __restrict__ partials, float* __restrict__ out, int n,
    size_t pos, float scale) {
#pragma clang fp contract(off)
  __shared__ float wred[4];
  float e = 0.f;
  for (int i = threadIdx.x; i < n; i += 256) e += partials[i];
#pragma unroll
  for (int off = 32; off > 0; off >>= 1) e += __shfl_down(e, off, 64);
  const int lane = threadIdx.x & 63, wv = threadIdx.x >> 6;
  if (lane == 0) wred[wv] = e;
  __syncthreads();
  if (threadIdx.x == 0)
    out[pos] = ((wred[0] + wred[1]) + (wred[2] + wred[3])) * scale;
}

extern "C" void kernel_launch(void* const* d_in, const int* in_sizes, int n_in,
                              void* d_out, int out_size, void* d_ws,
                              size_t ws_size, hipStream_t stream) {
  const float* x = (const float*)d_in[0];
  const float* roots = (const float*)d_in[1];
  float* out = (float*)d_out;
  float* partials = (float*)d_ws;

  const int nrow = in_sizes[0] / 8;
  const int nblocks = (nrow + 511) / 512;  // 512 rows per block (2/thread)

  e8_quant_kernel<<<nblocks, 256, 0, stream>>>(x, roots, out, partials, nrow);

  const size_t qerr_pos = (size_t)nrow * 12;
  const float scale = 1.0f / (float)((size_t)nrow * 8);  // 1/2^22, exact
  qerr_reduce_kernel<<<1, 256, 0, stream>>>(partials, out, 2 * nblocks,
                                            qerr_pos, scale);
}